// Round 9
// baseline (280.256 us; speedup 1.0000x reference)
//
#include <hip/hip_runtime.h>
#include <hip/hip_bf16.h>
#include <math.h>

#define B_ 2
#define T_ 2048
#define D_ 2048
#define H_ 16
#define KV_ 4
#define HD_ 128
#define REP_ 4
#define QKVSTR 3072

typedef __attribute__((ext_vector_type(8))) short s16x8;
typedef __attribute__((ext_vector_type(4))) short s16x4;
typedef __attribute__((ext_vector_type(4))) float f32x4;
typedef __attribute__((ext_vector_type(16))) float f32x16;
typedef __hip_bfloat16 bf16;

__device__ __forceinline__ short f2bf(float x) {
    bf16 h = __float2bfloat16(x);
    return *reinterpret_cast<short*>(&h);
}

__device__ __forceinline__ void gl2lds16(const void* g, void* l) {
    __builtin_amdgcn_global_load_lds(
        (const __attribute__((address_space(1))) char*)g,
        (__attribute__((address_space(3))) char*)l, 16, 0, 0);
}

// ---------------- fused prep: cast x -> bf16  +  all 4 weight transposes ----
// (see r5 notes: conflict-free u32 transpose, 33-word stride)
__global__ __launch_bounds__(256) void prep(const float* __restrict__ x,
                                            const float* __restrict__ Wq,
                                            const float* __restrict__ Wk,
                                            const float* __restrict__ Wv,
                                            const float* __restrict__ Wo,
                                            bf16* __restrict__ xb,
                                            bf16* __restrict__ Wqkvt,
                                            bf16* __restrict__ Wot,
                                            float qscale) {
    const int bid = blockIdx.x;
    const int t = threadIdx.x;
    if (bid < 4096) {
        int i = (bid * 256 + t) * 8;
        float4 a = *(const float4*)(x + i);
        float4 b = *(const float4*)(x + i + 4);
        short o[8] = {f2bf(a.x), f2bf(a.y), f2bf(a.z), f2bf(a.w),
                      f2bf(b.x), f2bf(b.y), f2bf(b.z), f2bf(b.w)};
        *(s16x8*)(xb + i) = *(const s16x8*)o;
        return;
    }
    __shared__ unsigned tileT[64 * 33];   // 8448 B, u32 = one k-pair
    const float* W; bf16* dst; int N; float scale; int seg;
    if (bid < 5120)      { seg = bid - 4096; W = Wq; dst = Wqkvt;                      N = 2048; scale = qscale; }
    else if (bid < 5376) { seg = bid - 5120; W = Wk; dst = Wqkvt + (size_t)2048 * D_;  N = 512;  scale = 1.f; }
    else if (bid < 5632) { seg = bid - 5376; W = Wv; dst = Wqkvt + (size_t)2560 * D_;  N = 512;  scale = 1.f; }
    else                 { seg = bid - 5632; W = Wo; dst = Wot;                        N = 2048; scale = 1.f; }
    const int k0 = (seg & 31) * 64, n0 = (seg >> 5) * 64;

    const int r2 = t >> 3;            // k-pair 0..31
    const int c0 = (t & 7) * 8;       // col offset 0..56
    const float* srcA = W + (size_t)(k0 + 2 * r2) * N + n0 + c0;
    const float* srcB = srcA + N;
    float4 a0 = *(const float4*)(srcA);
    float4 a1 = *(const float4*)(srcA + 4);
    float4 b0 = *(const float4*)(srcB);
    float4 b1 = *(const float4*)(srcB + 4);
    float ra[8] = {a0.x, a0.y, a0.z, a0.w, a1.x, a1.y, a1.z, a1.w};
    float rb[8] = {b0.x, b0.y, b0.z, b0.w, b1.x, b1.y, b1.z, b1.w};
    #pragma unroll
    for (int j = 0; j < 8; ++j) {
        unsigned p;
        asm("v_cvt_pk_bf16_f32 %0, %1, %2"
            : "=v"(p) : "v"(ra[j] * scale), "v"(rb[j] * scale));
        tileT[(c0 + j) * 33 + r2] = p;
    }
    __syncthreads();
    const int n = t >> 2, q = t & 3;
    union { unsigned u[8]; s16x8 v[2]; } ou;
    #pragma unroll
    for (int j = 0; j < 8; ++j) ou.u[j] = tileT[n * 33 + q * 8 + j];
    bf16* d = dst + (size_t)(n0 + n) * D_ + k0 + q * 16;
    *(s16x8*)(d)     = ou.v[0];
    *(s16x8*)(d + 8) = ou.v[1];
}

// ---- bf16 NT GEMM, 8-wave BMxBN tile, counted-vmcnt pipeline (T4) ---------
// (unchanged from r5 — see comments there; SQ_LDS_BANK_CONFLICT measured 0)
template<int MI, int NJ, typename OUTT, int ROUND, int WVT>
__global__ __launch_bounds__(512, 2) void gemm8(const bf16* __restrict__ A,
                                                const bf16* __restrict__ Bt,
                                                OUTT* __restrict__ C,
                                                bf16* __restrict__ Vtg,
                                                int M, int N, int K) {
    constexpr int ASZ = MI * 2048;          // shorts per A buffer (MI*32 x 64)
    constexpr int BSZ = NJ * 4096;          // shorts per B buffer (NJ*64 x 64)
    __shared__ short smem[2 * (ASZ + BSZ)];
    const int tid = threadIdx.x;
    const int lane = tid & 63;
    const int wave = tid >> 6;
    const int quad = lane >> 4;
    const int l16 = lane & 15;
    const int wr = wave >> 2, wc = wave & 3;      // 2 x 4 wave grid
    const int row0 = blockIdx.y * (MI * 32);
    const int col0 = blockIdx.x * (NJ * 64);
    const int NT = K >> 6;

    f32x4 acc[MI][NJ] = {};

    const bf16* Ap = A + (size_t)row0 * K;
    const bf16* Bp = Bt + (size_t)col0 * K;

    auto stage = [&](int t) {
        const int bo = (t & 1) * (ASZ + BSZ);
        const int k0 = t * 64;
        #pragma unroll
        for (int i = 0; i < MI / 2; ++i) {
            int g = i * 512 + tid;
            int row = g >> 3;
            int cs = (g & 7) ^ (row & 7);
            gl2lds16(Ap + (size_t)row * K + k0 + cs * 8, &smem[bo + g * 8]);
        }
        #pragma unroll
        for (int i = 0; i < NJ; ++i) {
            int g = i * 512 + tid;
            int row = g >> 3;
            int cs = (g & 7) ^ (row & 7);
            gl2lds16(Bp + (size_t)row * K + k0 + cs * 8, &smem[bo + ASZ + g * 8]);
        }
    };

    constexpr int VM = MI / 2 + NJ;         // loads per stage = in-flight count
    static_assert(VM == 6 || VM == 7, "add a vmcnt literal for this shape");

    stage(0);
    for (int t = 0; t < NT; ++t) {
        if (t + 1 < NT) {
            stage(t + 1);
            if constexpr (VM == 7) asm volatile("s_waitcnt vmcnt(7)" ::: "memory");
            else                   asm volatile("s_waitcnt vmcnt(6)" ::: "memory");
        } else {
            asm volatile("s_waitcnt vmcnt(0)" ::: "memory");
        }
        __builtin_amdgcn_s_barrier();
        asm volatile("" ::: "memory");

        const int bo = (t & 1) * (ASZ + BSZ);
        #pragma unroll
        for (int kk = 0; kk < 2; ++kk) {
            s16x8 af[MI], bfr[NJ];
            #pragma unroll
            for (int i = 0; i < MI; ++i) {
                int row = wr * (MI * 16) + i * 16 + l16;
                int c = (kk * 4 + quad) ^ (row & 7);
                af[i] = *(const s16x8*)&smem[bo + row * 64 + c * 8];
            }
            #pragma unroll
            for (int j = 0; j < NJ; ++j) {
                int row = wc * (NJ * 16) + j * 16 + l16;
                int c = (kk * 4 + quad) ^ (row & 7);
                bfr[j] = *(const s16x8*)&smem[bo + ASZ + row * 64 + c * 8];
            }
            __builtin_amdgcn_s_setprio(1);
            #pragma unroll
            for (int i = 0; i < MI; ++i)
                #pragma unroll
                for (int j = 0; j < NJ; ++j)
                    acc[i][j] = __builtin_amdgcn_mfma_f32_16x16x32_bf16(
                        af[i], bfr[j], acc[i][j], 0, 0, 0);
            __builtin_amdgcn_s_setprio(0);
        }
        asm volatile("s_waitcnt lgkmcnt(0)" ::: "memory");
        __builtin_amdgcn_s_barrier();
        asm volatile("" ::: "memory");
    }

    #pragma unroll
    for (int i = 0; i < MI; ++i) {
        #pragma unroll
        for (int j = 0; j < NJ; ++j) {
            const int col = col0 + wc * (NJ * 16) + j * 16 + l16;
            const int rowb = row0 + wr * (MI * 16) + i * 16 + quad * 4;
            #pragma unroll
            for (int r = 0; r < 4; ++r) {
                float v = acc[i][j][r];
                if (ROUND) v = rintf(v * 1e4f) * 1e-4f;
                if constexpr (sizeof(OUTT) == 2)
                    C[(size_t)(rowb + r) * N + col] = __float2bfloat16(v);
                else
                    C[(size_t)(rowb + r) * N + col] = v;
            }
            if constexpr (WVT) {
                if (col >= 2560) {
                    const int dcol = (col - 2560) & 127;
                    const int g = (col - 2560) >> 7;
                    const int b = rowb >> 11;
                    const int t = rowb & 2047;
                    short pk[4] = {f2bf(acc[i][j][0]), f2bf(acc[i][j][1]),
                                   f2bf(acc[i][j][2]), f2bf(acc[i][j][3])};
                    *(s16x4*)&Vtg[(size_t)((b * KV_ + g) * HD_ + dcol) * T_ + t] =
                        *(const s16x4*)pk;
                }
            }
        }
    }
}

// ---------------- MFMA flash attention v9c ---------------------------------
// = flash9 (75.8 us measured, original qt map restored — r8's "balanced
// pairing" remap REGRESSED to 83.7, dispatch-pairing model discarded)
// + two counter-backed fixes:
// 1. Conflict-free LDS swizzle. Old sigma(row)=row&mask: rows have stride
//    ≡ 0 mod 128 B so bank = (4c+w)%32 depends ONLY on chunk c; read lanes
//    {k,k+8,k+16,k+24} got the same c mod 8 (bit 3 of row doesn't move it)
//    -> 4-way conflict on EVERY QK/PV ds_read_b128 (SQ_LDS_BANK_CONFLICT
//    = 2.16M/dispatch). New sigma(row) = (row ^ (row>>3)) & mask spreads
//    the group to quads {k,k^1,k^2,k^3} -> conflict-free. Same sigma on
//    the pre-swizzled gl2lds SOURCE and the read (both-sides rule).
// 2. T5 s_setprio(1) around the QK and PV MFMA clusters (+4-7%, m191).
__global__ __launch_bounds__(256, 2) void flash9(const bf16* __restrict__ Q,
                                                 const bf16* __restrict__ K,
                                                 const bf16* __restrict__ Vtg,
                                                 bf16* __restrict__ O) {
    __shared__ short smem[32768];   // 2 buffers x (Kt [64s][128d] + Vt [128d][64s])

    const int h = blockIdx.x;
    const int b = blockIdx.y & 1;
    const int qt = 15 - (blockIdx.y >> 1);   // heavy blocks first (LPT)
    const int g = h >> 2;
    const int tid = threadIdx.x;
    const int lane = tid & 63;
    const int wave = tid >> 6;
    const int l32 = lane & 31;
    const int hi = lane >> 5;                // which k-half of the frag
    const int qw0 = qt * 128 + wave * 32;    // this wave's first q row
    const int qg = qw0 + l32;                // this lane's q row

    // Q fragments (B-operand): n=l32 (q), k = hi*8 + j (d); 8 k-tiles of 16
    s16x8 qf[8];
    {
        const bf16* qp = Q + (size_t)(b * T_ + qg) * QKVSTR + h * HD_ + hi * 8;
        #pragma unroll
        for (int kt = 0; kt < 8; ++kt) qf[kt] = *(const s16x8*)(qp + kt * 16);
    }

    const bf16* Kp = K + (size_t)(b * T_) * QKVSTR + g * HD_;
    const bf16* Vp = Vtg + (size_t)((b * KV_ + g) * HD_) * T_;

    float l_part = 0.f;
    f32x16 oacc[4] = {};

    const int jmax = 2 * qt + 1;

    // prologue: stage tile 0 into buffer 0
    #pragma unroll
    for (int i = 0; i < 4; ++i) {
        int g2 = i * 256 + tid;
        int s = g2 >> 4;
        int cs = (g2 & 15) ^ ((s ^ (s >> 3)) & 15);
        gl2lds16(Kp + (size_t)s * QKVSTR + cs * 8, &smem[g2 * 8]);
    }
    #pragma unroll
    for (int i = 0; i < 4; ++i) {
        int g2 = i * 256 + tid;
        int d = g2 >> 3;
        int cs = (g2 & 7) ^ ((d ^ (d >> 3)) & 7);
        gl2lds16(Vp + (size_t)d * T_ + cs * 8, &smem[8192 + g2 * 8]);
    }

    for (int j = 0; j <= jmax; ++j) {
        const int kb = (j & 1) << 14;        // 16384 shorts per buffer
        // drains tile j's loads (vmcnt(0) before s_barrier) AND ensures all
        // waves finished reading the buffer tile j+1 is about to overwrite
        __syncthreads();

        if (j < jmax) {                      // stage tile j+1 (block-uniform)
            const int s0n = (j + 1) * 64;
            const int nb = ((j + 1) & 1) << 14;
            #pragma unroll
            for (int i = 0; i < 4; ++i) {
                int g2 = i * 256 + tid;
                int s = g2 >> 4;
                int cs = (g2 & 15) ^ ((s ^ (s >> 3)) & 15);
                gl2lds16(Kp + (size_t)(s0n + s) * QKVSTR + cs * 8, &smem[nb + g2 * 8]);
            }
            #pragma unroll
            for (int i = 0; i < 4; ++i) {
                int g2 = i * 256 + tid;
                int d = g2 >> 3;
                int cs = (g2 & 7) ^ ((d ^ (d >> 3)) & 7);
                gl2lds16(Vp + (size_t)d * T_ + s0n + cs * 8, &smem[nb + 8192 + g2 * 8]);
            }
        }

        const int s0 = j * 64;
        if (s0 >= qw0 + 32) continue;        // tile fully masked for this wave

        // S = K·Q^T : sacc[mt] has n=q=l32, m=s (two 32-s halves)
        f32x16 sacc[2] = {};
        __builtin_amdgcn_s_setprio(1);
        #pragma unroll
        for (int kt = 0; kt < 8; ++kt) {
            #pragma unroll
            for (int mt = 0; mt < 2; ++mt) {
                int s = mt * 32 + l32;
                int c = (kt * 2 + hi) ^ ((s ^ (s >> 3)) & 15);
                const s16x8 kf = *(const s16x8*)&smem[kb + s * 128 + c * 8];
                sacc[mt] = __builtin_amdgcn_mfma_f32_32x32x16_bf16(
                    kf, qf[kt], sacc[mt], 0, 0, 0);
            }
        }
        __builtin_amdgcn_s_setprio(0);

        const bool diagw = (s0 + 63 > qw0);
        #pragma unroll
        for (int mt = 0; mt < 2; ++mt) {
            // static softmax: P = exp2(s) (scale folded into Wq); masked -> 0
            #pragma unroll
            for (int r = 0; r < 16; ++r) {
                float sv = sacc[mt][r];
                if (diagw) {
                    int sg = s0 + mt * 32 + (r & 3) + 8 * (r >> 2) + 4 * hi;
                    if (sg > qg) sv = -INFINITY;
                }
                float e = exp2f(sv);
                sacc[mt][r] = e;
                l_part += e;
            }
            // P -> bf16 A-frags in registers: regs o..o+7 cover the 16-s
            // k-tile kts; cvt_pk pairs + permlane32_swap fix the lane-half
            // split: swap(w01,w45) -> {A0,A2}, swap(w23,w67) -> {A1,A3}.
            #pragma unroll
            for (int kts = 0; kts < 2; ++kts) {
                const int o = kts * 8;
                unsigned w01, w23, w45, w67;
                asm("v_cvt_pk_bf16_f32 %0, %1, %2"
                    : "=v"(w01) : "v"(sacc[mt][o + 0]), "v"(sacc[mt][o + 1]));
                asm("v_cvt_pk_bf16_f32 %0, %1, %2"
                    : "=v"(w23) : "v"(sacc[mt][o + 2]), "v"(sacc[mt][o + 3]));
                asm("v_cvt_pk_bf16_f32 %0, %1, %2"
                    : "=v"(w45) : "v"(sacc[mt][o + 4]), "v"(sacc[mt][o + 5]));
                asm("v_cvt_pk_bf16_f32 %0, %1, %2"
                    : "=v"(w67) : "v"(sacc[mt][o + 6]), "v"(sacc[mt][o + 7]));
                asm("v_permlane32_swap_b32 %0, %1" : "+v"(w01), "+v"(w45));
                asm("v_permlane32_swap_b32 %0, %1" : "+v"(w23), "+v"(w67));
                union { unsigned u[4]; s16x8 v; } pu;
                pu.u[0] = w01; pu.u[1] = w23; pu.u[2] = w45; pu.u[3] = w67;
                const s16x8 pa = pu.v;
                // O += P·V : A=pa (m=q=l32, k=s), B=V (k=s, n=d=l32)
                __builtin_amdgcn_s_setprio(1);
                #pragma unroll
                for (int nt = 0; nt < 4; ++nt) {
                    int d = nt * 32 + l32;
                    int c = ((mt * 2 + kts) * 2 + hi) ^ ((d ^ (d >> 3)) & 7);
                    const s16x8 vf = *(const s16x8*)&smem[kb + 8192 + d * 64 + c * 8];
                    oacc[nt] = __builtin_amdgcn_mfma_f32_32x32x16_bf16(
                        pa, vf, oacc[nt], 0, 0, 0);
                }
                __builtin_amdgcn_s_setprio(0);
            }
        }
    }

    // full row sum: the other 32 s of each tile live in the lane^32 partner
    l_part += __shfl_xor(l_part, 32);
    const float invl = 1.f / l_part;     // valid for q = qw0 + l32

    // epilogue: oacc rows are q=(r&3)+8*(r>>2)+4*hi, cols d=nt*32+l32
    bf16* op = O + (size_t)(b * T_ + qw0) * (H_ * HD_) + h * HD_;
    #pragma unroll
    for (int r = 0; r < 16; ++r) {
        const int qrow = (r & 3) + 8 * (r >> 2) + 4 * hi;
        const float il = __shfl(invl, qrow);
        #pragma unroll
        for (int nt = 0; nt < 4; ++nt)
            op[(size_t)qrow * (H_ * HD_) + nt * 32 + l32] =
                __float2bfloat16(oacc[nt][r] * il);
    }
}

extern "C" void kernel_launch(void* const* d_in, const int* in_sizes, int n_in,
                              void* d_out, int out_size, void* d_ws, size_t ws_size,
                              hipStream_t stream) {
    const float* x  = (const float*)d_in[0];
    const float* Wq = (const float*)d_in[1];
    const float* Wk = (const float*)d_in[2];
    const float* Wv = (const float*)d_in[3];
    const float* Wo = (const float*)d_in[4];
    float* out = (float*)d_out;

    const size_t NR = (size_t)B_ * T_;               // 4096
    bf16* ws = (bf16*)d_ws;
    bf16* xb    = ws;                                 // 4096*2048
    bf16* Wqkvt = xb + NR * D_;                       // 3072*2048
    bf16* Wot   = Wqkvt + (size_t)QKVSTR * D_;        // 2048*2048
    bf16* QKVb  = Wot + (size_t)D_ * D_;              // 4096*3072
    bf16* Vtg   = QKVb + NR * QKVSTR;                 // 2*4*128*2048
    bf16* Ab    = Vtg + (size_t)B_ * KV_ * HD_ * T_;  // 4096*2048

    const float qscale = 1.4426950408889634f / sqrtf((float)HD_);

    prep<<<6656, 256, 0, stream>>>(x, Wq, Wk, Wv, Wo, xb, Wqkvt, Wot, qscale);

    // fused QKV projection (256x192 tiles, 256 blocks = exact CU coverage);
    // V columns also written transposed into Vtg
    gemm8<8, 3, bf16, 0, 1><<<dim3(QKVSTR / 192, NR / 256), 512, 0, stream>>>(
        xb, Wqkvt, QKVb, Vtg, (int)NR, QKVSTR, D_);

    flash9<<<dim3(H_, 32), 256, 0, stream>>>(QKVb, QKVb + 2048, Vtg, Ab);

    // output projection (128x256 tiles, 256 blocks)
    gemm8<4, 4, float, 1, 0><<<dim3(D_ / 256, NR / 128), 512, 0, stream>>>(
        Ab, Wot, out, nullptr, (int)NR, D_, H_ * HD_);
}

// Round 10
// 275.887 us; speedup vs baseline: 1.0158x; 1.0158x over previous
//
#include <hip/hip_runtime.h>
#include <hip/hip_bf16.h>
#include <math.h>

#define B_ 2
#define T_ 2048
#define D_ 2048
#define H_ 16
#define KV_ 4
#define HD_ 128
#define REP_ 4
#define QKVSTR 3072

typedef __attribute__((ext_vector_type(8))) short s16x8;
typedef __attribute__((ext_vector_type(4))) short s16x4;
typedef __attribute__((ext_vector_type(4))) float f32x4;
typedef __attribute__((ext_vector_type(16))) float f32x16;
typedef __hip_bfloat16 bf16;

__device__ __forceinline__ short f2bf(float x) {
    bf16 h = __float2bfloat16(x);
    return *reinterpret_cast<short*>(&h);
}

__device__ __forceinline__ void gl2lds16(const void* g, void* l) {
    __builtin_amdgcn_global_load_lds(
        (const __attribute__((address_space(1))) char*)g,
        (__attribute__((address_space(3))) char*)l, 16, 0, 0);
}

// ---------------- fused prep: cast x -> bf16  +  all 4 weight transposes ----
// (see r5 notes: conflict-free u32 transpose, 33-word stride)
__global__ __launch_bounds__(256) void prep(const float* __restrict__ x,
                                            const float* __restrict__ Wq,
                                            const float* __restrict__ Wk,
                                            const float* __restrict__ Wv,
                                            const float* __restrict__ Wo,
                                            bf16* __restrict__ xb,
                                            bf16* __restrict__ Wqkvt,
                                            bf16* __restrict__ Wot,
                                            float qscale) {
    const int bid = blockIdx.x;
    const int t = threadIdx.x;
    if (bid < 4096) {
        int i = (bid * 256 + t) * 8;
        float4 a = *(const float4*)(x + i);
        float4 b = *(const float4*)(x + i + 4);
        short o[8] = {f2bf(a.x), f2bf(a.y), f2bf(a.z), f2bf(a.w),
                      f2bf(b.x), f2bf(b.y), f2bf(b.z), f2bf(b.w)};
        *(s16x8*)(xb + i) = *(const s16x8*)o;
        return;
    }
    __shared__ unsigned tileT[64 * 33];   // 8448 B, u32 = one k-pair
    const float* W; bf16* dst; int N; float scale; int seg;
    if (bid < 5120)      { seg = bid - 4096; W = Wq; dst = Wqkvt;                      N = 2048; scale = qscale; }
    else if (bid < 5376) { seg = bid - 5120; W = Wk; dst = Wqkvt + (size_t)2048 * D_;  N = 512;  scale = 1.f; }
    else if (bid < 5632) { seg = bid - 5376; W = Wv; dst = Wqkvt + (size_t)2560 * D_;  N = 512;  scale = 1.f; }
    else                 { seg = bid - 5632; W = Wo; dst = Wot;                        N = 2048; scale = 1.f; }
    const int k0 = (seg & 31) * 64, n0 = (seg >> 5) * 64;

    const int r2 = t >> 3;            // k-pair 0..31
    const int c0 = (t & 7) * 8;       // col offset 0..56
    const float* srcA = W + (size_t)(k0 + 2 * r2) * N + n0 + c0;
    const float* srcB = srcA + N;
    float4 a0 = *(const float4*)(srcA);
    float4 a1 = *(const float4*)(srcA + 4);
    float4 b0 = *(const float4*)(srcB);
    float4 b1 = *(const float4*)(srcB + 4);
    float ra[8] = {a0.x, a0.y, a0.z, a0.w, a1.x, a1.y, a1.z, a1.w};
    float rb[8] = {b0.x, b0.y, b0.z, b0.w, b1.x, b1.y, b1.z, b1.w};
    #pragma unroll
    for (int j = 0; j < 8; ++j) {
        unsigned p;
        asm("v_cvt_pk_bf16_f32 %0, %1, %2"
            : "=v"(p) : "v"(ra[j] * scale), "v"(rb[j] * scale));
        tileT[(c0 + j) * 33 + r2] = p;
    }
    __syncthreads();
    const int n = t >> 2, q = t & 3;
    union { unsigned u[8]; s16x8 v[2]; } ou;
    #pragma unroll
    for (int j = 0; j < 8; ++j) ou.u[j] = tileT[n * 33 + q * 8 + j];
    bf16* d = dst + (size_t)(n0 + n) * D_ + k0 + q * 16;
    *(s16x8*)(d)     = ou.v[0];
    *(s16x8*)(d + 8) = ou.v[1];
}

// ---- bf16 NT GEMM, 8-wave BMxBN tile, counted-vmcnt pipeline (T4) ---------
// (unchanged from r5 — see comments there; SQ_LDS_BANK_CONFLICT measured 0)
template<int MI, int NJ, typename OUTT, int ROUND, int WVT>
__global__ __launch_bounds__(512, 2) void gemm8(const bf16* __restrict__ A,
                                                const bf16* __restrict__ Bt,
                                                OUTT* __restrict__ C,
                                                bf16* __restrict__ Vtg,
                                                int M, int N, int K) {
    constexpr int ASZ = MI * 2048;          // shorts per A buffer (MI*32 x 64)
    constexpr int BSZ = NJ * 4096;          // shorts per B buffer (NJ*64 x 64)
    __shared__ short smem[2 * (ASZ + BSZ)];
    const int tid = threadIdx.x;
    const int lane = tid & 63;
    const int wave = tid >> 6;
    const int quad = lane >> 4;
    const int l16 = lane & 15;
    const int wr = wave >> 2, wc = wave & 3;      // 2 x 4 wave grid
    const int row0 = blockIdx.y * (MI * 32);
    const int col0 = blockIdx.x * (NJ * 64);
    const int NT = K >> 6;

    f32x4 acc[MI][NJ] = {};

    const bf16* Ap = A + (size_t)row0 * K;
    const bf16* Bp = Bt + (size_t)col0 * K;

    auto stage = [&](int t) {
        const int bo = (t & 1) * (ASZ + BSZ);
        const int k0 = t * 64;
        #pragma unroll
        for (int i = 0; i < MI / 2; ++i) {
            int g = i * 512 + tid;
            int row = g >> 3;
            int cs = (g & 7) ^ (row & 7);
            gl2lds16(Ap + (size_t)row * K + k0 + cs * 8, &smem[bo + g * 8]);
        }
        #pragma unroll
        for (int i = 0; i < NJ; ++i) {
            int g = i * 512 + tid;
            int row = g >> 3;
            int cs = (g & 7) ^ (row & 7);
            gl2lds16(Bp + (size_t)row * K + k0 + cs * 8, &smem[bo + ASZ + g * 8]);
        }
    };

    constexpr int VM = MI / 2 + NJ;         // loads per stage = in-flight count
    static_assert(VM == 6 || VM == 7, "add a vmcnt literal for this shape");

    stage(0);
    for (int t = 0; t < NT; ++t) {
        if (t + 1 < NT) {
            stage(t + 1);
            if constexpr (VM == 7) asm volatile("s_waitcnt vmcnt(7)" ::: "memory");
            else                   asm volatile("s_waitcnt vmcnt(6)" ::: "memory");
        } else {
            asm volatile("s_waitcnt vmcnt(0)" ::: "memory");
        }
        __builtin_amdgcn_s_barrier();
        asm volatile("" ::: "memory");

        const int bo = (t & 1) * (ASZ + BSZ);
        #pragma unroll
        for (int kk = 0; kk < 2; ++kk) {
            s16x8 af[MI], bfr[NJ];
            #pragma unroll
            for (int i = 0; i < MI; ++i) {
                int row = wr * (MI * 16) + i * 16 + l16;
                int c = (kk * 4 + quad) ^ (row & 7);
                af[i] = *(const s16x8*)&smem[bo + row * 64 + c * 8];
            }
            #pragma unroll
            for (int j = 0; j < NJ; ++j) {
                int row = wc * (NJ * 16) + j * 16 + l16;
                int c = (kk * 4 + quad) ^ (row & 7);
                bfr[j] = *(const s16x8*)&smem[bo + ASZ + row * 64 + c * 8];
            }
            __builtin_amdgcn_s_setprio(1);
            #pragma unroll
            for (int i = 0; i < MI; ++i)
                #pragma unroll
                for (int j = 0; j < NJ; ++j)
                    acc[i][j] = __builtin_amdgcn_mfma_f32_16x16x32_bf16(
                        af[i], bfr[j], acc[i][j], 0, 0, 0);
            __builtin_amdgcn_s_setprio(0);
        }
        asm volatile("s_waitcnt lgkmcnt(0)" ::: "memory");
        __builtin_amdgcn_s_barrier();
        asm volatile("" ::: "memory");
    }

    #pragma unroll
    for (int i = 0; i < MI; ++i) {
        #pragma unroll
        for (int j = 0; j < NJ; ++j) {
            const int col = col0 + wc * (NJ * 16) + j * 16 + l16;
            const int rowb = row0 + wr * (MI * 16) + i * 16 + quad * 4;
            #pragma unroll
            for (int r = 0; r < 4; ++r) {
                float v = acc[i][j][r];
                if (ROUND) v = rintf(v * 1e4f) * 1e-4f;
                if constexpr (sizeof(OUTT) == 2)
                    C[(size_t)(rowb + r) * N + col] = __float2bfloat16(v);
                else
                    C[(size_t)(rowb + r) * N + col] = v;
            }
            if constexpr (WVT) {
                if (col >= 2560) {
                    const int dcol = (col - 2560) & 127;
                    const int g = (col - 2560) >> 7;
                    const int b = rowb >> 11;
                    const int t = rowb & 2047;
                    short pk[4] = {f2bf(acc[i][j][0]), f2bf(acc[i][j][1]),
                                   f2bf(acc[i][j][2]), f2bf(acc[i][j][3])};
                    *(s16x4*)&Vtg[(size_t)((b * KV_ + g) * HD_ + dcol) * T_ + t] =
                        *(const s16x4*)pk;
                }
            }
        }
    }
}

// ---------------- MFMA flash attention v9d ---------------------------------
// Base = flash9 (75.8 us measured: original qt map, NO setprio — r9 proved
// setprio in this barrier-lockstep 4-wave block costs time, m190-regime).
// One change vs that base: subtile-INVARIANT conflict-free LDS swizzle.
//   r9 confirmed the 4-way bank-quad conflict (2.16M -> 0) but its
//   sigma=(r^(r>>3))&mask pulled nt/mt bits into the chunk index ->
//   per-subtile address recompute + lost ds_read immediate-offset folding
//   (VALUBusy +3) -> net regression.
//   New sigma(r) = (r & mask) ^ ((r>>3) & 3):
//     * read rows r = mt*32+l32 (K) / nt*32+l32 (V): (r>>3)&3 = (l32>>3)&3
//       -> mt/nt-INVARIANT -> codegen identical to original flash9
//       (one address + immediate offsets per subtile loop).
//     * conflict groups {l32, l32+8, l32+16, l32+24} share r&7 but get
//       distinct (r>>3)&3 -> 4 distinct bank-quads; per 32-lane half each
//       quad serves exactly 4 lanes = b128 uniform optimum.
//     * staging uses the same sigma on the same row index (both-sides
//       rule); source permutation stays within each row's 128B -> coalesced.
__global__ __launch_bounds__(256, 2) void flash9(const bf16* __restrict__ Q,
                                                 const bf16* __restrict__ K,
                                                 const bf16* __restrict__ Vtg,
                                                 bf16* __restrict__ O) {
    __shared__ short smem[32768];   // 2 buffers x (Kt [64s][128d] + Vt [128d][64s])

    const int h = blockIdx.x;
    const int b = blockIdx.y & 1;
    const int qt = 15 - (blockIdx.y >> 1);   // heavy blocks first (LPT)
    const int g = h >> 2;
    const int tid = threadIdx.x;
    const int lane = tid & 63;
    const int wave = tid >> 6;
    const int l32 = lane & 31;
    const int hi = lane >> 5;                // which k-half of the frag
    const int qw0 = qt * 128 + wave * 32;    // this wave's first q row
    const int qg = qw0 + l32;                // this lane's q row

    // Q fragments (B-operand): n=l32 (q), k = hi*8 + j (d); 8 k-tiles of 16
    s16x8 qf[8];
    {
        const bf16* qp = Q + (size_t)(b * T_ + qg) * QKVSTR + h * HD_ + hi * 8;
        #pragma unroll
        for (int kt = 0; kt < 8; ++kt) qf[kt] = *(const s16x8*)(qp + kt * 16);
    }

    const bf16* Kp = K + (size_t)(b * T_) * QKVSTR + g * HD_;
    const bf16* Vp = Vtg + (size_t)((b * KV_ + g) * HD_) * T_;

    // lane-resident swizzle terms (subtile-invariant by construction)
    const int sigK = (l32 & 15) ^ ((l32 >> 3) & 3);
    const int sigV = (l32 & 7) ^ ((l32 >> 3) & 3);

    float l_part = 0.f;
    f32x16 oacc[4] = {};

    const int jmax = 2 * qt + 1;

    // prologue: stage tile 0 into buffer 0
    #pragma unroll
    for (int i = 0; i < 4; ++i) {
        int g2 = i * 256 + tid;
        int s = g2 >> 4;
        int cs = (g2 & 15) ^ ((s & 15) ^ ((s >> 3) & 3));
        gl2lds16(Kp + (size_t)s * QKVSTR + cs * 8, &smem[g2 * 8]);
    }
    #pragma unroll
    for (int i = 0; i < 4; ++i) {
        int g2 = i * 256 + tid;
        int d = g2 >> 3;
        int cs = (g2 & 7) ^ ((d & 7) ^ ((d >> 3) & 3));
        gl2lds16(Vp + (size_t)d * T_ + cs * 8, &smem[8192 + g2 * 8]);
    }

    for (int j = 0; j <= jmax; ++j) {
        const int kb = (j & 1) << 14;        // 16384 shorts per buffer
        // drains tile j's loads (vmcnt(0) before s_barrier) AND ensures all
        // waves finished reading the buffer tile j+1 is about to overwrite
        __syncthreads();

        if (j < jmax) {                      // stage tile j+1 (block-uniform)
            const int s0n = (j + 1) * 64;
            const int nb = ((j + 1) & 1) << 14;
            #pragma unroll
            for (int i = 0; i < 4; ++i) {
                int g2 = i * 256 + tid;
                int s = g2 >> 4;
                int cs = (g2 & 15) ^ ((s & 15) ^ ((s >> 3) & 3));
                gl2lds16(Kp + (size_t)(s0n + s) * QKVSTR + cs * 8, &smem[nb + g2 * 8]);
            }
            #pragma unroll
            for (int i = 0; i < 4; ++i) {
                int g2 = i * 256 + tid;
                int d = g2 >> 3;
                int cs = (g2 & 7) ^ ((d & 7) ^ ((d >> 3) & 3));
                gl2lds16(Vp + (size_t)d * T_ + s0n + cs * 8, &smem[nb + 8192 + g2 * 8]);
            }
        }

        const int s0 = j * 64;
        if (s0 >= qw0 + 32) continue;        // tile fully masked for this wave

        // S = K·Q^T : sacc[mt] has n=q=l32, m=s (two 32-s halves)
        f32x16 sacc[2] = {};
        #pragma unroll
        for (int kt = 0; kt < 8; ++kt) {
            #pragma unroll
            for (int mt = 0; mt < 2; ++mt) {
                int s = mt * 32 + l32;
                int c = (kt * 2 + hi) ^ sigK;
                const s16x8 kf = *(const s16x8*)&smem[kb + s * 128 + c * 8];
                sacc[mt] = __builtin_amdgcn_mfma_f32_32x32x16_bf16(
                    kf, qf[kt], sacc[mt], 0, 0, 0);
            }
        }

        const bool diagw = (s0 + 63 > qw0);
        #pragma unroll
        for (int mt = 0; mt < 2; ++mt) {
            // static softmax: P = exp2(s) (scale folded into Wq); masked -> 0
            #pragma unroll
            for (int r = 0; r < 16; ++r) {
                float sv = sacc[mt][r];
                if (diagw) {
                    int sg = s0 + mt * 32 + (r & 3) + 8 * (r >> 2) + 4 * hi;
                    if (sg > qg) sv = -INFINITY;
                }
                float e = exp2f(sv);
                sacc[mt][r] = e;
                l_part += e;
            }
            // P -> bf16 A-frags in registers: regs o..o+7 cover the 16-s
            // k-tile kts; cvt_pk pairs + permlane32_swap fix the lane-half
            // split: swap(w01,w45) -> {A0,A2}, swap(w23,w67) -> {A1,A3}.
            #pragma unroll
            for (int kts = 0; kts < 2; ++kts) {
                const int o = kts * 8;
                unsigned w01, w23, w45, w67;
                asm("v_cvt_pk_bf16_f32 %0, %1, %2"
                    : "=v"(w01) : "v"(sacc[mt][o + 0]), "v"(sacc[mt][o + 1]));
                asm("v_cvt_pk_bf16_f32 %0, %1, %2"
                    : "=v"(w23) : "v"(sacc[mt][o + 2]), "v"(sacc[mt][o + 3]));
                asm("v_cvt_pk_bf16_f32 %0, %1, %2"
                    : "=v"(w45) : "v"(sacc[mt][o + 4]), "v"(sacc[mt][o + 5]));
                asm("v_cvt_pk_bf16_f32 %0, %1, %2"
                    : "=v"(w67) : "v"(sacc[mt][o + 6]), "v"(sacc[mt][o + 7]));
                asm("v_permlane32_swap_b32 %0, %1" : "+v"(w01), "+v"(w45));
                asm("v_permlane32_swap_b32 %0, %1" : "+v"(w23), "+v"(w67));
                union { unsigned u[4]; s16x8 v; } pu;
                pu.u[0] = w01; pu.u[1] = w23; pu.u[2] = w45; pu.u[3] = w67;
                const s16x8 pa = pu.v;
                // O += P·V : A=pa (m=q=l32, k=s), B=V (k=s, n=d=l32)
                #pragma unroll
                for (int nt = 0; nt < 4; ++nt) {
                    int d = nt * 32 + l32;
                    int c = ((mt * 2 + kts) * 2 + hi) ^ sigV;
                    const s16x8 vf = *(const s16x8*)&smem[kb + 8192 + d * 64 + c * 8];
                    oacc[nt] = __builtin_amdgcn_mfma_f32_32x32x16_bf16(
                        pa, vf, oacc[nt], 0, 0, 0);
                }
            }
        }
    }

    // full row sum: the other 32 s of each tile live in the lane^32 partner
    l_part += __shfl_xor(l_part, 32);
    const float invl = 1.f / l_part;     // valid for q = qw0 + l32

    // epilogue: oacc rows are q=(r&3)+8*(r>>2)+4*hi, cols d=nt*32+l32
    bf16* op = O + (size_t)(b * T_ + qw0) * (H_ * HD_) + h * HD_;
    #pragma unroll
    for (int r = 0; r < 16; ++r) {
        const int qrow = (r & 3) + 8 * (r >> 2) + 4 * hi;
        const float il = __shfl(invl, qrow);
        #pragma unroll
        for (int nt = 0; nt < 4; ++nt)
            op[(size_t)qrow * (H_ * HD_) + nt * 32 + l32] =
                __float2bfloat16(oacc[nt][r] * il);
    }
}

extern "C" void kernel_launch(void* const* d_in, const int* in_sizes, int n_in,
                              void* d_out, int out_size, void* d_ws, size_t ws_size,
                              hipStream_t stream) {
    const float* x  = (const float*)d_in[0];
    const float* Wq = (const float*)d_in[1];
    const float* Wk = (const float*)d_in[2];
    const float* Wv = (const float*)d_in[3];
    const float* Wo = (const float*)d_in[4];
    float* out = (float*)d_out;

    const size_t NR = (size_t)B_ * T_;               // 4096
    bf16* ws = (bf16*)d_ws;
    bf16* xb    = ws;                                 // 4096*2048
    bf16* Wqkvt = xb + NR * D_;                       // 3072*2048
    bf16* Wot   = Wqkvt + (size_t)QKVSTR * D_;        // 2048*2048
    bf16* QKVb  = Wot + (size_t)D_ * D_;              // 4096*3072
    bf16* Vtg   = QKVb + NR * QKVSTR;                 // 2*4*128*2048
    bf16* Ab    = Vtg + (size_t)B_ * KV_ * HD_ * T_;  // 4096*2048

    const float qscale = 1.4426950408889634f / sqrtf((float)HD_);

    prep<<<6656, 256, 0, stream>>>(x, Wq, Wk, Wv, Wo, xb, Wqkvt, Wot, qscale);

    // fused QKV projection (256x192 tiles, 256 blocks = exact CU coverage);
    // V columns also written transposed into Vtg
    gemm8<8, 3, bf16, 0, 1><<<dim3(QKVSTR / 192, NR / 256), 512, 0, stream>>>(
        xb, Wqkvt, QKVb, Vtg, (int)NR, QKVSTR, D_);

    flash9<<<dim3(H_, 32), 256, 0, stream>>>(QKVb, QKVb + 2048, Vtg, Ab);

    // output projection (128x256 tiles, 256 blocks)
    gemm8<4, 4, float, 1, 0><<<dim3(D_ / 256, NR / 128), 512, 0, stream>>>(
        Ab, Wot, out, nullptr, (int)NR, D_, H_ * HD_);
}